// Round 2
// baseline (234.076 us; speedup 1.0000x reference)
//
#include <hip/hip_runtime.h>
#include <stdint.h>

typedef __bf16 bf16;
typedef __bf16 bf16x8 __attribute__((ext_vector_type(8)));
typedef float f32x4 __attribute__((ext_vector_type(4)));

typedef __attribute__((address_space(1))) void gvoid_t;
typedef __attribute__((address_space(3))) void lvoid_t;

__device__ __forceinline__ void gload16(const void* src, void* lds) {
    __builtin_amdgcn_global_load_lds((gvoid_t*)src, (lvoid_t*)lds, 16, 0, 0);
}

// ---------------- f32 -> bf16 convert ----------------
__global__ __launch_bounds__(256) void cvt_kernel(const float* __restrict__ in,
                                                  bf16* __restrict__ out, int n8) {
    int idx = blockIdx.x * 256 + threadIdx.x;
    int stride = gridDim.x * 256;
    for (int i = idx; i < n8; i += stride) {
        const float4* p = (const float4*)in;
        float4 a = p[(long)i * 2], b = p[(long)i * 2 + 1];
        bf16x8 o;
        o[0] = (bf16)a.x; o[1] = (bf16)a.y; o[2] = (bf16)a.z; o[3] = (bf16)a.w;
        o[4] = (bf16)b.x; o[5] = (bf16)b.y; o[6] = (bf16)b.z; o[7] = (bf16)b.w;
        ((bf16x8*)out)[i] = o;
    }
}

// ---------------- GEMM: C[M,N] = A[M,K] * W[N,K]^T (m97 structure) ----------------
template <bool F32OUT>
__global__ __launch_bounds__(256) void gemm_bt(const bf16* __restrict__ A,
                                               const bf16* __restrict__ W,
                                               const float* __restrict__ bias,
                                               void* __restrict__ Cout,
                                               const int M, const int N, const int K) {
    __shared__ __align__(16) bf16 Alds[4096];  // [128][32]
    __shared__ __align__(16) bf16 Blds[4096];  // [128][32]
    const int t = threadIdx.x;
    const int wid = t >> 6, lane = t & 63;
    const int g = lane >> 4, c = lane & 15;
    const int wm = wid >> 1, wn = wid & 1;
    const long bm = (long)blockIdx.y * 128, bn = (long)blockIdx.x * 128;

    f32x4 acc[4][4] = {};

    const int arow = t >> 2;          // 0..63
    const int acol = (t & 3) * 8;     // elem offset
    const bf16* Asrc = A + (bm + arow) * (long)K + acol;
    const bf16* Bsrc = W + (bn + arow) * (long)K + acol;
    bf16* adst = Alds + wid * 512;
    bf16* bdst = Blds + wid * 512;

    for (int k0 = 0; k0 < K; k0 += 32) {
        gload16(Asrc + k0, adst);
        gload16(Asrc + k0 + (long)64 * K, adst + 2048);
        gload16(Bsrc + k0, bdst);
        gload16(Bsrc + k0 + (long)64 * K, bdst + 2048);
        __syncthreads();
        bf16x8 af[4], bfr[4];
#pragma unroll
        for (int mt = 0; mt < 4; ++mt)
            af[mt] = *(const bf16x8*)(Alds + (wm * 64 + mt * 16 + c) * 32 + g * 8);
#pragma unroll
        for (int nt = 0; nt < 4; ++nt)
            bfr[nt] = *(const bf16x8*)(Blds + (wn * 64 + nt * 16 + c) * 32 + g * 8);
#pragma unroll
        for (int mt = 0; mt < 4; ++mt)
#pragma unroll
            for (int nt = 0; nt < 4; ++nt)
                acc[mt][nt] = __builtin_amdgcn_mfma_f32_16x16x32_bf16(af[mt], bfr[nt],
                                                                      acc[mt][nt], 0, 0, 0);
        __syncthreads();
    }
#pragma unroll
    for (int mt = 0; mt < 4; ++mt) {
#pragma unroll
        for (int nt = 0; nt < 4; ++nt) {
#pragma unroll
            for (int i = 0; i < 4; ++i) {
                const long row = bm + wm * 64 + mt * 16 + g * 4 + i;
                const long col = bn + wn * 64 + nt * 16 + c;
                if constexpr (F32OUT) {
                    ((float*)Cout)[row * N + col] = acc[mt][nt][i] + bias[col];
                } else {
                    ((bf16*)Cout)[row * N + col] = (bf16)acc[mt][nt][i];
                }
            }
        }
    }
}

// ---------------- Flash attention (correctness-first) ----------------
// qkv: [4096 rows][3072] bf16, row = b*2048+s; q at +0, k at +1024, v at +2048 (head h: +h*64)
// attno: [4096][1024] bf16
__global__ __launch_bounds__(256) void flash_kernel(const bf16* __restrict__ qkv,
                                                    bf16* __restrict__ attno) {
    __shared__ __align__(16) bf16 Vt[5120];  // V^T tile: [d=64][stride 80] holding kv=64
    __shared__ __align__(16) bf16 Pl[5120];  // 4 waves x [16 rows][stride 80]

    const int t = threadIdx.x;
    const int wid = t >> 6, lane = t & 63;
    const int g = lane >> 4, c = lane & 15;
    const int qb = blockIdx.x, bh = blockIdx.y;
    const int b = bh >> 4, h = bh & 15;
    const int rowbase = b * 2048;
    const int q0 = qb * 64 + wid * 16;

    // Q fragments in registers: A[row=q0+c][k=d], d = g*8+e (+32 for qf1)
    bf16x8 qf0, qf1;
    {
        const long qoff = (long)(rowbase + q0 + c) * 3072 + h * 64 + g * 8;
        qf0 = *(const bf16x8*)(qkv + qoff);
        qf1 = *(const bf16x8*)(qkv + qoff + 32);
    }

    float mrow[4], lrow[4];
    f32x4 oacc[4] = {};
#pragma unroll
    for (int i = 0; i < 4; ++i) { mrow[i] = -1e30f; lrow[i] = 0.f; }

    // V staging: thread handles rows (t>>3) and (t>>3)+32, cols (t&7)*8..+7
    const int vr = t >> 3;
    const int vc = (t & 7) * 8;
    const bf16* vsrc = qkv + (long)(rowbase + vr) * 3072 + 2048 + h * 64 + vc;
    const bf16* kbase = qkv + (long)rowbase * 3072 + 1024 + h * 64;
    bf16* Pw = Pl + wid * 1280;

    for (int kv0 = 0; kv0 < 2048; kv0 += 64) {
        // ---- stage V transposed into LDS ----
        bf16x8 v0 = *(const bf16x8*)(vsrc + (long)kv0 * 3072);
        bf16x8 v1 = *(const bf16x8*)(vsrc + (long)(kv0 + 32) * 3072);
#pragma unroll
        for (int e = 0; e < 8; ++e) {
            Vt[(vc + e) * 80 + vr] = v0[e];
            Vt[(vc + e) * 80 + vr + 32] = v1[e];
        }

        // ---- S = Q K^T (K B-frags direct from global; k-mapping matches Q's) ----
        f32x4 sc[4];
#pragma unroll
        for (int nt = 0; nt < 4; ++nt) {
            const bf16* kr = kbase + (long)(kv0 + nt * 16 + c) * 3072;
            bf16x8 kf0 = *(const bf16x8*)(kr + g * 8);
            bf16x8 kf1 = *(const bf16x8*)(kr + 32 + g * 8);
            f32x4 a = {};
            a = __builtin_amdgcn_mfma_f32_16x16x32_bf16(qf0, kf0, a, 0, 0, 0);
            a = __builtin_amdgcn_mfma_f32_16x16x32_bf16(qf1, kf1, a, 0, 0, 0);
            sc[nt] = a;
        }
        __syncthreads();  // V writes visible to all waves (K loads overlapped above)

        // ---- online softmax: row r = g*4+i lives across the 16 lanes sharing g ----
        float tm[4];
#pragma unroll
        for (int i = 0; i < 4; ++i) {
            sc[0][i] *= 0.125f; sc[1][i] *= 0.125f; sc[2][i] *= 0.125f; sc[3][i] *= 0.125f;
            tm[i] = fmaxf(fmaxf(sc[0][i], sc[1][i]), fmaxf(sc[2][i], sc[3][i]));
        }
#pragma unroll
        for (int m = 1; m <= 8; m <<= 1) {
#pragma unroll
            for (int i = 0; i < 4; ++i) tm[i] = fmaxf(tm[i], __shfl_xor(tm[i], m));
        }
        float fr[4];
#pragma unroll
        for (int i = 0; i < 4; ++i) {
            float mn = fmaxf(mrow[i], tm[i]);
            fr[i] = __expf(mrow[i] - mn);
            mrow[i] = mn;
        }
        float rs[4] = {0.f, 0.f, 0.f, 0.f};
#pragma unroll
        for (int nt = 0; nt < 4; ++nt) {
#pragma unroll
            for (int i = 0; i < 4; ++i) {
                float p = __expf(sc[nt][i] - mrow[i]);
                sc[nt][i] = p;
                rs[i] += p;
            }
        }
#pragma unroll
        for (int m = 1; m <= 8; m <<= 1) {
#pragma unroll
            for (int i = 0; i < 4; ++i) rs[i] += __shfl_xor(rs[i], m);
        }
#pragma unroll
        for (int i = 0; i < 4; ++i) lrow[i] = lrow[i] * fr[i] + rs[i];
#pragma unroll
        for (int nt = 0; nt < 4; ++nt)
#pragma unroll
            for (int i = 0; i < 4; ++i) oacc[nt][i] *= fr[i];

        // ---- P -> per-wave LDS (C-layout -> A-layout rearrange) ----
#pragma unroll
        for (int nt = 0; nt < 4; ++nt)
#pragma unroll
            for (int i = 0; i < 4; ++i)
                Pw[(g * 4 + i) * 80 + nt * 16 + c] = (bf16)sc[nt][i];

        // ---- O += P V ----
#pragma unroll
        for (int kk = 0; kk < 2; ++kk) {
            bf16x8 pf = *(const bf16x8*)(Pw + c * 80 + kk * 32 + g * 8);
#pragma unroll
            for (int nt = 0; nt < 4; ++nt) {
                bf16x8 vf = *(const bf16x8*)(Vt + (nt * 16 + c) * 80 + kk * 32 + g * 8);
                oacc[nt] = __builtin_amdgcn_mfma_f32_16x16x32_bf16(pf, vf, oacc[nt], 0, 0, 0);
            }
        }
        __syncthreads();  // all waves done with Vt before next tile overwrites it
    }

    // epilogue: normalize and store bf16
#pragma unroll
    for (int nt = 0; nt < 4; ++nt) {
#pragma unroll
        for (int i = 0; i < 4; ++i) {
            float o = oacc[nt][i] / lrow[i];
            attno[(long)(rowbase + q0 + g * 4 + i) * 1024 + h * 64 + nt * 16 + c] = (bf16)o;
        }
    }
}

// ---------------- launch ----------------
extern "C" void kernel_launch(void* const* d_in, const int* in_sizes, int n_in,
                              void* d_out, int out_size, void* d_ws, size_t ws_size,
                              hipStream_t stream) {
    const float* x = (const float*)d_in[0];      // [2,2048,1024]
    const float* wqkv = (const float*)d_in[1];   // [3072,1024]
    const float* wproj = (const float*)d_in[2];  // [1024,1024]
    const float* bproj = (const float*)d_in[3];  // [1024]

    char* ws = (char*)d_ws;
    bf16* xb     = (bf16*)(ws);                  // 8 MB
    bf16* wqkvb  = (bf16*)(ws + 8388608);        // 6 MB
    bf16* wprojb = (bf16*)(ws + 14680064);       // 2 MB
    bf16* qkv    = (bf16*)(ws + 16777216);       // 24 MB
    bf16* attno  = (bf16*)(ws + 41943040);       // 8 MB
    if (ws_size < 50331648) return;

    cvt_kernel<<<2048, 256, 0, stream>>>(x, xb, 524288);
    cvt_kernel<<<1536, 256, 0, stream>>>(wqkv, wqkvb, 393216);
    cvt_kernel<<<512, 256, 0, stream>>>(wproj, wprojb, 131072);

    // qkv[4096,3072] = xb[4096,1024] @ wqkvb[3072,1024]^T
    gemm_bt<false><<<dim3(24, 32), 256, 0, stream>>>(xb, wqkvb, nullptr, qkv, 4096, 3072, 1024);

    // attention per (qb, b*h)
    flash_kernel<<<dim3(32, 32), 256, 0, stream>>>(qkv, attno);

    // out[4096,1024] = attno @ wprojb^T + bias (f32)
    gemm_bt<true><<<dim3(8, 32), 256, 0, stream>>>(attno, wprojb, bproj, d_out, 4096, 1024, 1024);
}